// Round 1
// baseline (307.103 us; speedup 1.0000x reference)
//
#include <hip/hip_runtime.h>
#include <math.h>

typedef __attribute__((ext_vector_type(8))) short bf16x8;
typedef __attribute__((ext_vector_type(8))) unsigned short u16x8;
typedef __attribute__((ext_vector_type(4))) unsigned short u16x4;
typedef __attribute__((ext_vector_type(4))) float f32x4;
typedef unsigned short u16;

__device__ __forceinline__ u16 f2bf(float f) {
  unsigned u = __builtin_bit_cast(unsigned, f);
  return (u16)((u + 0x7FFFu + ((u >> 16) & 1u)) >> 16);
}

__device__ __forceinline__ void gload_lds16(const void* g, void* l) {
  __builtin_amdgcn_global_load_lds((const __attribute__((address_space(1))) void*)g,
                                   (__attribute__((address_space(3))) void*)l, 16, 0, 0);
}

// ---------------- prep: f32 -> bf16 ----------------
__global__ __launch_bounds__(256) void cvt_bf16_kernel(const float* __restrict__ in,
                                                       u16* __restrict__ out, int n4) {
  int i = blockIdx.x * 256 + threadIdx.x;
  if (i >= n4) return;
  const float4 v = ((const float4*)in)[i];
  u16x4 o = { f2bf(v.x), f2bf(v.y), f2bf(v.z), f2bf(v.w) };
  ((u16x4*)out)[i] = o;
}

// ---------------- prep: relu(cp) transposed to [t][c] bf16 ----------------
__global__ __launch_bounds__(256) void relu_t_kernel(const float* __restrict__ cp,
                                                     u16* __restrict__ x0t) {
  const int cb = blockIdx.x & 31;   // channel tile (2048/64)
  const int tb = blockIdx.x >> 5;   // frame tile (4096/64)
  __shared__ __attribute__((aligned(16))) float tile[64][65];
  const int tid = threadIdx.x;
  const int r0 = tid >> 4, i4 = (tid & 15) * 4;
  #pragma unroll
  for (int rr = 0; rr < 64; rr += 16) {
    const float4 v = *(const float4*)(cp + (size_t)(cb * 64 + r0 + rr) * 4096 + tb * 64 + i4);
    tile[r0 + rr][i4 + 0] = fmaxf(v.x, 0.f);
    tile[r0 + rr][i4 + 1] = fmaxf(v.y, 0.f);
    tile[r0 + rr][i4 + 2] = fmaxf(v.z, 0.f);
    tile[r0 + rr][i4 + 3] = fmaxf(v.w, 0.f);
  }
  __syncthreads();
  #pragma unroll
  for (int it = 0; it < 2; ++it) {
    const int chunk = it * 256 + tid;
    const int i = chunk >> 3, rp = (chunk & 7) * 8;
    u16x8 o;
    #pragma unroll
    for (int q = 0; q < 8; ++q) o[q] = f2bf(tile[rp + q][i]);
    *(u16x8*)(x0t + (size_t)(tb * 64 + i) * 2048 + cb * 64 + rp) = o;
  }
}

// ---------------- IIR: y[t] = dd*(x[t] + y[t-1]), write yT[t][c] bf16 ----------------
__global__ __launch_bounds__(128) void iir_kernel(const float* __restrict__ x,
                                                  const float* __restrict__ decays,
                                                  u16* __restrict__ yT) {
  const int tid = threadIdx.x;
  const int c0 = blockIdx.x * 128;
  __shared__ __attribute__((aligned(16))) float xs[128][65];
  __shared__ __attribute__((aligned(16))) u16 ys[64][136];
  const float sig = 1.0f / (1.0f + expf(-decays[c0 + tid]));
  const float dd = 1e-12f + 0.5f + 0.5f * sig;
  float yv = 0.0f;
  for (int t0 = 0; t0 < 4096; t0 += 64) {
    #pragma unroll
    for (int it = 0; it < 16; ++it) {
      const int idx = it * 128 + tid;
      const int r = idx >> 4, iv = (idx & 15) * 4;
      const float4 v = *(const float4*)(x + (size_t)(c0 + r) * 4096 + t0 + iv);
      xs[r][iv + 0] = v.x; xs[r][iv + 1] = v.y; xs[r][iv + 2] = v.z; xs[r][iv + 3] = v.w;
    }
    __syncthreads();
    #pragma unroll
    for (int i = 0; i < 64; ++i) {
      yv = dd * (xs[tid][i] + yv);
      ys[i][tid] = f2bf(yv);
    }
    __syncthreads();
    #pragma unroll
    for (int it = 0; it < 8; ++it) {
      const int chunk = it * 128 + tid;
      const int i = chunk >> 4, cpv = (chunk & 15) * 8;
      u16x8 v = *(const u16x8*)&ys[i][cpv];
      *(u16x8*)(yT + (size_t)(t0 + i) * 2048 + c0 + cpv) = v;
    }
    __syncthreads();
  }
}

// ---------------- GEMM: C[M][N] = A[M][K] @ Bt[N][K]^T, 128x128 tile ----------------
// MODE 0: plain f32 store. MODE 1: +orig, tanh(*g), f32 store + bf16 transposed store.
template <int MODE>
__global__ __launch_bounds__(256, 2) void gemm_kernel(
    const u16* __restrict__ A, const u16* __restrict__ Bt, float* __restrict__ C,
    int M, int N, int K, int nbx,
    const float* __restrict__ orig, const float* __restrict__ gains,
    u16* __restrict__ CbT) {
  __shared__ __attribute__((aligned(16))) u16 As[128 * 32];
  __shared__ __attribute__((aligned(16))) u16 Bs[128 * 32];
  __shared__ float gs[128];
  const int tid = threadIdx.x;
  const int lane = tid & 63, wid = tid >> 6;
  const int bid = blockIdx.x;
  const int bm = bid / nbx, bn = bid % nbx;

  if (MODE == 1 && tid < 128) gs[tid] = 5.0f / (1.0f + expf(-gains[bm * 128 + tid]));

  const int wr = wid >> 1, wc = wid & 1;
  const int ca = wid * 64 + lane;
  const int rA = ca >> 2, kp = (ca & 3) * 8;

  const u16* gA0 = A  + (size_t)(bm * 128 + rA)      * K + kp;
  const u16* gA1 = A  + (size_t)(bm * 128 + rA + 64) * K + kp;
  const u16* gB0 = Bt + (size_t)(bn * 128 + rA)      * K + kp;
  const u16* gB1 = Bt + (size_t)(bn * 128 + rA + 64) * K + kp;
  u16* lA0 = As + wid * 64 * 8;          // HW adds lane*16B
  u16* lA1 = As + (256 + wid * 64) * 8;
  u16* lB0 = Bs + wid * 64 * 8;
  u16* lB1 = Bs + (256 + wid * 64) * 8;

  f32x4 acc[4][4];
  #pragma unroll
  for (int i = 0; i < 4; ++i)
    #pragma unroll
    for (int j = 0; j < 4; ++j) acc[i][j] = (f32x4){0.f, 0.f, 0.f, 0.f};

  const int arow = lane & 15, khalf = (lane >> 4) * 8;

  for (int k0 = 0; k0 < K; k0 += 32) {
    __syncthreads();
    gload_lds16(gA0 + k0, lA0);
    gload_lds16(gA1 + k0, lA1);
    gload_lds16(gB0 + k0, lB0);
    gload_lds16(gB1 + k0, lB1);
    asm volatile("s_waitcnt vmcnt(0)" ::: "memory");
    __syncthreads();
    bf16x8 af[4], bfv[4];
    #pragma unroll
    for (int mi = 0; mi < 4; ++mi)
      af[mi] = *(const bf16x8*)(As + (wr * 64 + mi * 16 + arow) * 32 + khalf);
    #pragma unroll
    for (int ni = 0; ni < 4; ++ni)
      bfv[ni] = *(const bf16x8*)(Bs + (wc * 64 + ni * 16 + arow) * 32 + khalf);
    #pragma unroll
    for (int mi = 0; mi < 4; ++mi)
      #pragma unroll
      for (int ni = 0; ni < 4; ++ni)
        acc[mi][ni] = __builtin_amdgcn_mfma_f32_16x16x32_bf16(af[mi], bfv[ni], acc[mi][ni], 0, 0, 0);
  }

  const int rb = bm * 128 + wr * 64 + (lane >> 4) * 4;
  const int cb = bn * 128 + wc * 64 + (lane & 15);
  #pragma unroll
  for (int mi = 0; mi < 4; ++mi) {
    #pragma unroll
    for (int ni = 0; ni < 4; ++ni) {
      const int row0 = rb + mi * 16;
      const int col = cb + ni * 16;
      f32x4 v = acc[mi][ni];
      if (MODE == 1) {
        float cpv[4];
        #pragma unroll
        for (int j = 0; j < 4; ++j) {
          float t = v[j] + orig[(size_t)(row0 + j) * N + col];
          cpv[j] = tanhf(t * gs[row0 + j - bm * 128]);
          C[(size_t)(row0 + j) * N + col] = cpv[j];
        }
        u16x4 o = { f2bf(cpv[0]), f2bf(cpv[1]), f2bf(cpv[2]), f2bf(cpv[3]) };
        *(u16x4*)(CbT + (size_t)col * 2048 + row0) = o;
      } else {
        #pragma unroll
        for (int j = 0; j < 4; ++j)
          C[(size_t)(row0 + j) * N + col] = v[j];
      }
    }
  }
}

extern "C" void kernel_launch(void* const* d_in, const int* in_sizes, int n_in,
                              void* d_out, int out_size, void* d_ws, size_t ws_size,
                              hipStream_t stream) {
  const float* cp     = (const float*)d_in[0];
  const float* w1     = (const float*)d_in[1];
  const float* w2     = (const float*)d_in[2];
  const float* audio  = (const float*)d_in[3];
  const float* decays = (const float*)d_in[4];
  const float* gains  = (const float*)d_in[5];

  float* out0 = (float*)d_out;                   // audio_out: [t][w] flat
  float* out1 = out0 + (size_t)2048 * 4096;      // cp_out: [c][t]

  char* ws = (char*)d_ws;
  u16*   w1b    = (u16*)(ws);                    //  8 MB
  u16*   w2b    = (u16*)(ws + 8388608);          //  8 MB
  u16*   audiob = (u16*)(ws + 16777216);         //  8 MB
  float* orig   = (float*)(ws + 25165824);       // 32 MB
  u16*   yT     = (u16*)(ws + 58720256);         // 16 MB
  u16*   x0t    = (u16*)(ws + 75497472);         // 16 MB
  u16*   cpbT   = x0t;                           // reuse after GEMM1

  cvt_bf16_kernel<<<4096, 256, 0, stream>>>(w1, w1b, 1048576);
  cvt_bf16_kernel<<<4096, 256, 0, stream>>>(w2, w2b, 1048576);
  cvt_bf16_kernel<<<4096, 256, 0, stream>>>(audio, audiob, 1048576);
  relu_t_kernel<<<2048, 256, 0, stream>>>(cp, x0t);

  // x = w1 @ relu(cp)  -> orig[2048][4096]
  gemm_kernel<0><<<512, 256, 0, stream>>>(w1b, x0t, orig, 2048, 4096, 2048, 32,
                                          nullptr, nullptr, nullptr);
  // y = IIR(orig) -> yT[4096][2048] bf16
  iir_kernel<<<16, 128, 0, stream>>>(orig, decays, yT);
  // x2 = w2 @ y + orig; cp_out = tanh(x2*g) -> out1 f32, cpbT[t][c] bf16
  gemm_kernel<1><<<512, 256, 0, stream>>>(w2b, yT, out1, 2048, 4096, 2048, 32,
                                          orig, gains, cpbT);
  // audio_out[t][w] = sum_j cp_out[j][t]*audio[w][j] = cpbT @ audiob^T
  gemm_kernel<0><<<512, 256, 0, stream>>>(cpbT, audiob, out0, 4096, 2048, 2048, 16,
                                          nullptr, nullptr, nullptr);
}

// Round 2
// 217.673 us; speedup vs baseline: 1.4108x; 1.4108x over previous
//
#include <hip/hip_runtime.h>
#include <math.h>

typedef __attribute__((ext_vector_type(8))) short bf16x8;
typedef __attribute__((ext_vector_type(8))) unsigned short u16x8;
typedef __attribute__((ext_vector_type(4))) unsigned short u16x4;
typedef __attribute__((ext_vector_type(4))) float f32x4;
typedef unsigned short u16;

__device__ __forceinline__ u16 f2bf(float f) {
  unsigned u = __builtin_bit_cast(unsigned, f);
  return (u16)((u + 0x7FFFu + ((u >> 16) & 1u)) >> 16);
}

__device__ __forceinline__ void gload_lds16(const void* g, void* l) {
  __builtin_amdgcn_global_load_lds((const __attribute__((address_space(1))) void*)g,
                                   (__attribute__((address_space(3))) void*)l, 16, 0, 0);
}

__device__ __forceinline__ float decay_of(float d) {
  return 1e-12f + 0.5f + 0.5f / (1.0f + expf(-d));
}

// ---------------- prep: f32 -> bf16 ----------------
__global__ __launch_bounds__(256) void cvt_bf16_kernel(const float* __restrict__ in,
                                                       u16* __restrict__ out, int n4) {
  int i = blockIdx.x * 256 + threadIdx.x;
  if (i >= n4) return;
  const float4 v = ((const float4*)in)[i];
  u16x4 o = { f2bf(v.x), f2bf(v.y), f2bf(v.z), f2bf(v.w) };
  ((u16x4*)out)[i] = o;
}

// ---------------- prep: relu(cp) transposed to [t][c] bf16 ----------------
__global__ __launch_bounds__(256) void relu_t_kernel(const float* __restrict__ cp,
                                                     u16* __restrict__ x0t) {
  const int cb = blockIdx.x & 31;   // channel tile (2048/64)
  const int tb = blockIdx.x >> 5;   // frame tile (4096/64)
  __shared__ __attribute__((aligned(16))) float tile[64][65];
  const int tid = threadIdx.x;
  const int r0 = tid >> 4, i4 = (tid & 15) * 4;
  #pragma unroll
  for (int rr = 0; rr < 64; rr += 16) {
    const float4 v = *(const float4*)(cp + (size_t)(cb * 64 + r0 + rr) * 4096 + tb * 64 + i4);
    tile[r0 + rr][i4 + 0] = fmaxf(v.x, 0.f);
    tile[r0 + rr][i4 + 1] = fmaxf(v.y, 0.f);
    tile[r0 + rr][i4 + 2] = fmaxf(v.z, 0.f);
    tile[r0 + rr][i4 + 3] = fmaxf(v.w, 0.f);
  }
  __syncthreads();
  #pragma unroll
  for (int it = 0; it < 2; ++it) {
    const int chunk = it * 256 + tid;
    const int i = chunk >> 3, rp = (chunk & 7) * 8;
    u16x8 o;
    #pragma unroll
    for (int q = 0; q < 8; ++q) o[q] = f2bf(tile[rp + q][i]);
    *(u16x8*)(x0t + (size_t)(tb * 64 + i) * 2048 + cb * 64 + rp) = o;
  }
}

// ---------------- IIR pass 1: per-chunk local scan, write chunk-end L[ck][c] ----------------
__global__ __launch_bounds__(128) void iir_partial_kernel(const float* __restrict__ x,
                                                          const float* __restrict__ decays,
                                                          float* __restrict__ L) {
  const int tid = threadIdx.x;
  const int cb = blockIdx.x & 15;   // channel tile (2048/128)
  const int ck = blockIdx.x >> 4;   // time chunk (4096/64)
  const int c0 = cb * 128, t0 = ck * 64;
  __shared__ __attribute__((aligned(16))) float xs[128][65];
  const float dd = decay_of(decays[c0 + tid]);
  #pragma unroll
  for (int it = 0; it < 16; ++it) {
    const int idx = it * 128 + tid;
    const int r = idx >> 4, iv = (idx & 15) * 4;
    const float4 v = *(const float4*)(x + (size_t)(c0 + r) * 4096 + t0 + iv);
    xs[r][iv + 0] = v.x; xs[r][iv + 1] = v.y; xs[r][iv + 2] = v.z; xs[r][iv + 3] = v.w;
  }
  __syncthreads();
  float yv = 0.0f;
  #pragma unroll
  for (int i = 0; i < 64; ++i) yv = dd * (xs[tid][i] + yv);
  L[ck * 2048 + c0 + tid] = yv;
}

// ---------------- IIR pass 2: scan chunk carries; Cin[ck][c] = C_{ck-1} ----------------
__global__ __launch_bounds__(128) void iir_carry_kernel(const float* __restrict__ L,
                                                        const float* __restrict__ decays,
                                                        float* __restrict__ Cin) {
  const int c = blockIdx.x * 128 + threadIdx.x;
  const float dd = decay_of(decays[c]);
  float A = dd;
  #pragma unroll
  for (int p = 0; p < 6; ++p) A = A * A;   // dd^64
  float carry = 0.0f;
  for (int j = 0; j < 64; ++j) {
    Cin[j * 2048 + c] = carry;             // C_{j-1}
    carry = L[j * 2048 + c] + A * carry;   // C_j
  }
}

// ---------------- IIR pass 3: seeded local scan, write yT[t][c] bf16 ----------------
__global__ __launch_bounds__(128) void iir_apply_kernel(const float* __restrict__ x,
                                                        const float* __restrict__ decays,
                                                        const float* __restrict__ Cin,
                                                        u16* __restrict__ yT) {
  const int tid = threadIdx.x;
  const int cb = blockIdx.x & 15;
  const int ck = blockIdx.x >> 4;
  const int c0 = cb * 128, t0 = ck * 64;
  __shared__ __attribute__((aligned(16))) float xs[128][65];
  __shared__ __attribute__((aligned(16))) u16 ys[64][136];
  const float dd = decay_of(decays[c0 + tid]);
  const float carry = Cin[ck * 2048 + c0 + tid];
  #pragma unroll
  for (int it = 0; it < 16; ++it) {
    const int idx = it * 128 + tid;
    const int r = idx >> 4, iv = (idx & 15) * 4;
    const float4 v = *(const float4*)(x + (size_t)(c0 + r) * 4096 + t0 + iv);
    xs[r][iv + 0] = v.x; xs[r][iv + 1] = v.y; xs[r][iv + 2] = v.z; xs[r][iv + 3] = v.w;
  }
  __syncthreads();
  float yv = carry;
  #pragma unroll
  for (int i = 0; i < 64; ++i) {
    yv = dd * (xs[tid][i] + yv);
    ys[i][tid] = f2bf(yv);
  }
  __syncthreads();
  #pragma unroll
  for (int it = 0; it < 8; ++it) {
    const int chunk = it * 128 + tid;
    const int i = chunk >> 4, cpv = (chunk & 15) * 8;
    u16x8 v = *(const u16x8*)&ys[i][cpv];
    *(u16x8*)(yT + (size_t)(t0 + i) * 2048 + c0 + cpv) = v;
  }
}

// ---------------- GEMM: C[M][N] = A[M][K] @ Bt[N][K]^T, 128x128 tile ----------------
template <int MODE>
__global__ __launch_bounds__(256, 2) void gemm_kernel(
    const u16* __restrict__ A, const u16* __restrict__ Bt, float* __restrict__ C,
    int M, int N, int K, int nbx,
    const float* __restrict__ orig, const float* __restrict__ gains,
    u16* __restrict__ CbT) {
  __shared__ __attribute__((aligned(16))) u16 As[128 * 32];
  __shared__ __attribute__((aligned(16))) u16 Bs[128 * 32];
  __shared__ float gs[128];
  const int tid = threadIdx.x;
  const int lane = tid & 63, wid = tid >> 6;
  const int bid = blockIdx.x;
  const int bm = bid / nbx, bn = bid % nbx;

  if (MODE == 1 && tid < 128) gs[tid] = 5.0f / (1.0f + expf(-gains[bm * 128 + tid]));

  const int wr = wid >> 1, wc = wid & 1;
  const int ca = wid * 64 + lane;
  const int rA = ca >> 2, kp = (ca & 3) * 8;

  const u16* gA0 = A  + (size_t)(bm * 128 + rA)      * K + kp;
  const u16* gA1 = A  + (size_t)(bm * 128 + rA + 64) * K + kp;
  const u16* gB0 = Bt + (size_t)(bn * 128 + rA)      * K + kp;
  const u16* gB1 = Bt + (size_t)(bn * 128 + rA + 64) * K + kp;
  u16* lA0 = As + wid * 64 * 8;
  u16* lA1 = As + (256 + wid * 64) * 8;
  u16* lB0 = Bs + wid * 64 * 8;
  u16* lB1 = Bs + (256 + wid * 64) * 8;

  f32x4 acc[4][4];
  #pragma unroll
  for (int i = 0; i < 4; ++i)
    #pragma unroll
    for (int j = 0; j < 4; ++j) acc[i][j] = (f32x4){0.f, 0.f, 0.f, 0.f};

  const int arow = lane & 15, khalf = (lane >> 4) * 8;

  for (int k0 = 0; k0 < K; k0 += 32) {
    __syncthreads();
    gload_lds16(gA0 + k0, lA0);
    gload_lds16(gA1 + k0, lA1);
    gload_lds16(gB0 + k0, lB0);
    gload_lds16(gB1 + k0, lB1);
    asm volatile("s_waitcnt vmcnt(0)" ::: "memory");
    __syncthreads();
    bf16x8 af[4], bfv[4];
    #pragma unroll
    for (int mi = 0; mi < 4; ++mi)
      af[mi] = *(const bf16x8*)(As + (wr * 64 + mi * 16 + arow) * 32 + khalf);
    #pragma unroll
    for (int ni = 0; ni < 4; ++ni)
      bfv[ni] = *(const bf16x8*)(Bs + (wc * 64 + ni * 16 + arow) * 32 + khalf);
    #pragma unroll
    for (int mi = 0; mi < 4; ++mi)
      #pragma unroll
      for (int ni = 0; ni < 4; ++ni)
        acc[mi][ni] = __builtin_amdgcn_mfma_f32_16x16x32_bf16(af[mi], bfv[ni], acc[mi][ni], 0, 0, 0);
  }

  const int rb = bm * 128 + wr * 64 + (lane >> 4) * 4;
  const int cb = bn * 128 + wc * 64 + (lane & 15);
  #pragma unroll
  for (int mi = 0; mi < 4; ++mi) {
    #pragma unroll
    for (int ni = 0; ni < 4; ++ni) {
      const int row0 = rb + mi * 16;
      const int col = cb + ni * 16;
      f32x4 v = acc[mi][ni];
      if (MODE == 1) {
        float cpv[4];
        #pragma unroll
        for (int j = 0; j < 4; ++j) {
          float t = v[j] + orig[(size_t)(row0 + j) * N + col];
          cpv[j] = tanhf(t * gs[row0 + j - bm * 128]);
          C[(size_t)(row0 + j) * N + col] = cpv[j];
        }
        u16x4 o = { f2bf(cpv[0]), f2bf(cpv[1]), f2bf(cpv[2]), f2bf(cpv[3]) };
        *(u16x4*)(CbT + (size_t)col * 2048 + row0) = o;
      } else {
        #pragma unroll
        for (int j = 0; j < 4; ++j)
          C[(size_t)(row0 + j) * N + col] = v[j];
      }
    }
  }
}

extern "C" void kernel_launch(void* const* d_in, const int* in_sizes, int n_in,
                              void* d_out, int out_size, void* d_ws, size_t ws_size,
                              hipStream_t stream) {
  const float* cp     = (const float*)d_in[0];
  const float* w1     = (const float*)d_in[1];
  const float* w2     = (const float*)d_in[2];
  const float* audio  = (const float*)d_in[3];
  const float* decays = (const float*)d_in[4];
  const float* gains  = (const float*)d_in[5];

  float* out0 = (float*)d_out;                   // audio_out: [t][w] flat
  float* out1 = out0 + (size_t)2048 * 4096;      // cp_out: [c][t]

  char* ws = (char*)d_ws;
  u16*   w1b    = (u16*)(ws);                    //  8 MB
  u16*   w2b    = (u16*)(ws + 8388608);          //  8 MB
  u16*   audiob = (u16*)(ws + 16777216);         //  8 MB
  float* orig   = (float*)(ws + 25165824);       // 32 MB
  u16*   yT     = (u16*)(ws + 58720256);         // 16 MB
  u16*   x0t    = (u16*)(ws + 75497472);         // 16 MB
  u16*   cpbT   = x0t;                           // reuse after GEMM1
  // L/Cin overlap the x0t/cpbT region: x0t is dead after GEMM1, cpbT is
  // written only by GEMM2 which runs after iir_apply completes. 512 KB each.
  float* Lbuf   = (float*)(ws + 75497472);
  float* Cin    = (float*)(ws + 75497472 + 524288);

  cvt_bf16_kernel<<<4096, 256, 0, stream>>>(w1, w1b, 1048576);
  cvt_bf16_kernel<<<4096, 256, 0, stream>>>(w2, w2b, 1048576);
  cvt_bf16_kernel<<<4096, 256, 0, stream>>>(audio, audiob, 1048576);
  relu_t_kernel<<<2048, 256, 0, stream>>>(cp, x0t);

  // x = w1 @ relu(cp)  -> orig[2048][4096]
  gemm_kernel<0><<<512, 256, 0, stream>>>(w1b, x0t, orig, 2048, 4096, 2048, 32,
                                          nullptr, nullptr, nullptr);
  // y = IIR(orig) -> yT[4096][2048] bf16, via blocked scan
  iir_partial_kernel<<<1024, 128, 0, stream>>>(orig, decays, Lbuf);
  iir_carry_kernel<<<16, 128, 0, stream>>>(Lbuf, decays, Cin);
  iir_apply_kernel<<<1024, 128, 0, stream>>>(orig, decays, Cin, yT);
  // x2 = w2 @ y + orig; cp_out = tanh(x2*g) -> out1 f32, cpbT[t][c] bf16
  gemm_kernel<1><<<512, 256, 0, stream>>>(w2b, yT, out1, 2048, 4096, 2048, 32,
                                          orig, gains, cpbT);
  // audio_out[t][w] = cpbT @ audiob^T
  gemm_kernel<0><<<512, 256, 0, stream>>>(cpbT, audiob, out0, 4096, 2048, 2048, 16,
                                          nullptr, nullptr, nullptr);
}